// Round 17
// baseline (149.297 us; speedup 1.0000x reference)
//
#include <hip/hip_runtime.h>
#include <stdint.h>

#define HIDDEN 2048
#define EXPERTS 64
#define T_TOTAL 8192

// ====== GEMM v5: barrier-free per-wave pipeline + fused last-block combine ======
// Compute path UNCHANGED from R15 (steady 40 us, VALUBusy ~35%, 0 conflicts, no spill).
// New: per row-block atomic ticket; the LAST split block (of NS) combines the NS part
// slabs for its 128 rows in fixed ascending order -> cur. Saves the combine kernel
// launch and overlaps its 32 MB of reads with the GEMM tail. Handoff = R2-R8's proven
// __threadfence + agent-scope atomic pattern. Result bit-identical to snn_combine<NS>.
#define BM 128
#define BK 16

#define GLOAD16(g, l) __builtin_amdgcn_global_load_lds(                        \
        (const __attribute__((address_space(1))) unsigned int*)(g),            \
        (__attribute__((address_space(3))) unsigned int*)(l), 16, 0, 0)
#define FENCE() asm volatile("" ::: "memory")

template <int KS, int NS>
__global__ __launch_bounds__(128) void snn_gemm_pw(
        const float* __restrict__ A, const float* __restrict__ W,
        float* __restrict__ P, float* __restrict__ cur, int* __restrict__ cnt) {
    __shared__ float Aw[2][2][64 * BK];        // [wave][buf] 4 KB each
    __shared__ float Ww[2][2][BK * EXPERTS];   // [wave][buf] 4 KB each  -> 32 KB total

    const int t    = threadIdx.x;   // 0..127
    const int lane = t & 63;
    const int wv   = t >> 6;        // independent wave id
    const int rg   = lane >> 3;     // 0..7 : local rows rg*8..+7
    const int eg   = lane & 7;      // 0..7 : experts eg*8..+7
    const long row0 = (long)blockIdx.x * BM + (long)wv * 64;   // this wave's rows
    const int  k0   = blockIdx.y * KS;
    float* Pout = P + (long)blockIdx.y * ((long)T_TOTAL * EXPERTS);

    const float* aSrc[4];
#pragma unroll
    for (int p = 0; p < 4; ++p) {
        const int rl = p * 16 + (lane >> 2);
        const int cb = (lane & 3) ^ ((rl >> 3) & 3);
        aSrc[p] = &A[(row0 + rl) * HIDDEN + k0 + cb * 4];
    }
    const float* wSrc[4];
#pragma unroll
    for (int p = 0; p < 4; ++p)
        wSrc[p] = &W[(long)(k0 + p * 4 + (lane >> 4)) * EXPERTS + (lane & 15) * 4];

    auto stage = [&](int tile, int buf) {
        const int  aoff = tile * BK;
        const long woff = (long)tile * BK * EXPERTS;
#pragma unroll
        for (int p = 0; p < 4; ++p)
            GLOAD16(aSrc[p] + aoff, &Aw[wv][buf][p * 256]);   // +lane*16B by HW
#pragma unroll
        for (int p = 0; p < 4; ++p)
            GLOAD16(wSrc[p] + woff, &Ww[wv][buf][p * 256]);
    };

    float acc[8][8];
#pragma unroll
    for (int i = 0; i < 8; ++i)
#pragma unroll
        for (int j = 0; j < 8; ++j) acc[i][j] = 0.0f;

    stage(0, 0);

    constexpr int NTILE = KS / BK;
    int buf = 0;
    for (int tile = 0; tile < NTILE; ++tile) {
        if (tile + 1 < NTILE) {
            FENCE();
            stage(tile + 1, buf ^ 1);
            asm volatile("s_waitcnt vmcnt(8)" ::: "memory");   // tile t landed; t+1 in flight
        } else {
            asm volatile("s_waitcnt vmcnt(0)" ::: "memory");
        }
        FENCE();

        const float* ab = &Aw[wv][buf][0];
        const float* wb = &Ww[wv][buf][0];
        const int swz = rg & 3;
#pragma unroll
        for (int q = 0; q < BK / 4; ++q) {
            const int qs = (q ^ swz) * 4;
            float4 a4[8];
#pragma unroll
            for (int i = 0; i < 8; ++i)
                a4[i] = *reinterpret_cast<const float4*>(&ab[(rg * 8 + i) * BK + qs]);
            float4 w0[4], w1[4];
#pragma unroll
            for (int ki = 0; ki < 4; ++ki) {
                w0[ki] = *reinterpret_cast<const float4*>(&wb[(q * 4 + ki) * EXPERTS + eg * 8]);
                w1[ki] = *reinterpret_cast<const float4*>(&wb[(q * 4 + ki) * EXPERTS + eg * 8 + 4]);
            }
#pragma unroll
            for (int ki = 0; ki < 4; ++ki) {   // k ascending: q outer, ki inner
#pragma unroll
                for (int i = 0; i < 8; ++i) {
                    const float av = (&a4[i].x)[ki];
                    acc[i][0] = fmaf(av, w0[ki].x, acc[i][0]);
                    acc[i][1] = fmaf(av, w0[ki].y, acc[i][1]);
                    acc[i][2] = fmaf(av, w0[ki].z, acc[i][2]);
                    acc[i][3] = fmaf(av, w0[ki].w, acc[i][3]);
                    acc[i][4] = fmaf(av, w1[ki].x, acc[i][4]);
                    acc[i][5] = fmaf(av, w1[ki].y, acc[i][5]);
                    acc[i][6] = fmaf(av, w1[ki].z, acc[i][6]);
                    acc[i][7] = fmaf(av, w1[ki].w, acc[i][7]);
                }
            }
        }
        buf ^= 1;
    }

#pragma unroll
    for (int i = 0; i < 8; ++i) {
        float* base = &Pout[(row0 + rg * 8 + i) * EXPERTS + eg * 8];
        *reinterpret_cast<float4*>(base)     = make_float4(acc[i][0], acc[i][1], acc[i][2], acc[i][3]);
        *reinterpret_cast<float4*>(base + 4) = make_float4(acc[i][4], acc[i][5], acc[i][6], acc[i][7]);
    }

    // ---- fused fixed-order combine: last split block of this row-block does it ----
    if constexpr (NS > 1) {
        __shared__ int isLast;
        __syncthreads();                       // all C-stores retired (vmcnt drain at barrier)
        if (t == 0) {
            __threadfence();                   // release our slab writes to agent scope
            const int old = __hip_atomic_fetch_add(&cnt[blockIdx.x], 1,
                                __ATOMIC_ACQ_REL, __HIP_MEMORY_SCOPE_AGENT);
            isLast = (old == NS - 1) ? 1 : 0;
        }
        __syncthreads();
        if (isLast) {
            if (t == 0) __threadfence();       // acquire: see all NS slabs
            __syncthreads();
            const long b4 = (long)blockIdx.x * (BM * EXPERTS / 4);
            const float4* p4 = reinterpret_cast<const float4*>(P);
            float4* c4 = reinterpret_cast<float4*>(cur);
            for (int i = t; i < BM * EXPERTS / 4; i += 128) {
                float4 s = p4[b4 + i];
#pragma unroll
                for (int k = 1; k < NS; ++k) {   // ((p0+p1)+p2)+... ascending, as before
                    const float4 v = p4[b4 + i + (long)k * (T_TOTAL * EXPERTS / 4)];
                    s.x += v.x; s.y += v.y; s.z += v.z; s.w += v.w;
                }
                c4[b4 + i] = s;
            }
        }
    }
}

// ========= Scan: zero-sync overlap (warm-up 256 steps) + fused softmax =========
// Block w computes steps [w*128-256, w*128+128) from zero state; 0.9^256 forgetting
// makes the output-window state exact (whp bitwise). No flags/states/fences.
#define NCHUNK 64
#define CSTEPS (T_TOTAL / NCHUNK)   // 128
#define WARM   256

template <bool STORE>
__device__ __forceinline__ void lif_chunk(const float (&cbuf)[32], float* __restrict__ smp,
                                          int orow, int e, float& mp, float& refr) {
#pragma clang fp contract(off)
#pragma unroll
    for (int j = 0; j < 32; ++j) {
        const float term   = (refr <= 0.0f) ? cbuf[j] : 0.0f;
        const float mp_pre = mp * 0.9f + term;
        if constexpr (STORE) smp[(orow + j) * EXPERTS + e] = mp_pre;
        const bool spike = mp_pre > 1.0f;
        mp = spike ? 0.0f : mp_pre;
        const float rdec = fmaxf(refr - 0.1f, 0.0f);
        refr = spike ? 1.0f : rdec;
    }
}

__global__ __launch_bounds__(256) void snn_scan_ov(const float* __restrict__ cur,
                                                   float* __restrict__ out) {
    __shared__ float smp[CSTEPS * EXPERTS];   // 32 KB
    const int tid = threadIdx.x;
    const int w   = blockIdx.x;

    if (tid < 64) {
        const int e     = tid;
        const int t0abs = w * CSTEPS;
        const int s0    = (t0abs >= WARM) ? (t0abs - WARM) : 0;
        const int nwarm = t0abs - s0;              // 0, 128 or 256 (mult of 32)
        const int cwarm = nwarm >> 5;
        const int nc    = cwarm + (CSTEPS >> 5);   // 4, 8 or 12 (even)
        const float* cb = cur + (long)s0 * EXPERTS + e;

        float mp = 0.0f, refr = 0.0f;
        float bufA[32], bufB[32];
#pragma unroll
        for (int j = 0; j < 32; ++j) bufA[j] = cb[j * EXPERTS] * 0.1f;

        for (int c2 = 0; c2 < nc; c2 += 2) {
            if (c2 + 1 < nc)
#pragma unroll
                for (int j = 0; j < 32; ++j) bufB[j] = cb[((c2 + 1) * 32 + j) * EXPERTS] * 0.1f;
            if (c2 >= cwarm) lif_chunk<true >(bufA, smp, c2 * 32 - nwarm, e, mp, refr);
            else             lif_chunk<false>(bufA, smp, 0, e, mp, refr);
            if (c2 + 2 < nc)
#pragma unroll
                for (int j = 0; j < 32; ++j) bufA[j] = cb[((c2 + 2) * 32 + j) * EXPERTS] * 0.1f;
            if (c2 + 1 >= cwarm) lif_chunk<true >(bufB, smp, (c2 + 1) * 32 - nwarm, e, mp, refr);
            else                 lif_chunk<false>(bufB, smp, 0, e, mp, refr);
        }
    }
    __syncthreads();

    // ---- fused routing softmax: wave wvid handles rows wvid*32 .. +31 ----
    const int lane = tid & 63;
    const int wvid = tid >> 6;
    const float em1 = expf(-1.0f);
#pragma unroll 4
    for (int r = wvid * 32; r < wvid * 32 + 32; ++r) {
        const float v = smp[r * EXPERTS + lane];
        const bool spike = v > 1.0f;
        const unsigned long long ball = __ballot(spike);
        float res;
        if (ball != 0ull) {
            const int n = __popcll(ball);
            const float denom = (float)n + (float)(EXPERTS - n) * em1;
            res = spike ? (1.0f / denom) : (em1 / denom);
        } else {
            float m = v;
#pragma unroll
            for (int off = 32; off >= 1; off >>= 1)
                m = fmaxf(m, __shfl_xor(m, off, 64));
            const float p = expf(v - m);
            float s = p;
#pragma unroll
            for (int off = 32; off >= 1; off >>= 1)
                s += __shfl_xor(s, off, 64);
            res = p / s;
        }
        out[((long)w * CSTEPS + r) * EXPERTS + lane] = res;
    }
}

// ---------------------------------------------------------------------------
extern "C" void kernel_launch(void* const* d_in, const int* in_sizes, int n_in,
                              void* d_out, int out_size, void* d_ws, size_t ws_size,
                              hipStream_t stream) {
    const float* hs = (const float*)d_in[0];   // [4,2048,2048] f32
    const float* w  = (const float*)d_in[1];   // [2048,64] f32
    float* out = (float*)d_out;                // [4,2048,64] f32

    char*  ws   = (char*)d_ws;
    int*   cnt  = (int*)ws;                    // 64 ints (memset below)
    float* cur  = (float*)(ws + (1u << 20));   // 2 MB @ 1 MB
    float* part = (float*)(ws + (4u << 20));   // up to 16 x 2 MB @ 4 MB

    const size_t slab = (size_t)T_TOTAL * EXPERTS * sizeof(float);   // 2 MB

    if (ws_size >= (4u << 20) + 16 * slab) {            // 36 MB (R10 evidence: ws ~262 MB)
        hipMemsetAsync(cnt, 0, (T_TOTAL / BM) * sizeof(int), stream);
        snn_gemm_pw<HIDDEN / 16, 16><<<dim3(T_TOTAL / BM, 16), dim3(128), 0, stream>>>(hs, w, part, cur, cnt);
    } else if (ws_size >= (4u << 20) + 8 * slab) {
        hipMemsetAsync(cnt, 0, (T_TOTAL / BM) * sizeof(int), stream);
        snn_gemm_pw<HIDDEN / 8, 8><<<dim3(T_TOTAL / BM, 8), dim3(128), 0, stream>>>(hs, w, part, cur, cnt);
    } else {
        snn_gemm_pw<HIDDEN, 1><<<dim3(T_TOTAL / BM, 1), dim3(128), 0, stream>>>(hs, w, cur, cur, cnt);
    }
    snn_scan_ov<<<dim3(NCHUNK), dim3(256), 0, stream>>>(cur, out);
}

// Round 18
// 59.942 us; speedup vs baseline: 2.4907x; 2.4907x over previous
//
#include <hip/hip_runtime.h>
#include <stdint.h>

#define HIDDEN 2048
#define EXPERTS 64
#define T_TOTAL 8192

// ====== GEMM v5: barrier-free per-wave pipeline, all loads via global_load_lds ======
// VERBATIM R15 (steady 40 us, VALUBusy ~35%, 0 conflicts, no spill). R16/R17 proved
// fusing combine anywhere into this kernel or the scan regresses; keep 3-kernel shape.
#define BM 128
#define BK 16

#define GLOAD16(g, l) __builtin_amdgcn_global_load_lds(                        \
        (const __attribute__((address_space(1))) unsigned int*)(g),            \
        (__attribute__((address_space(3))) unsigned int*)(l), 16, 0, 0)
#define FENCE() asm volatile("" ::: "memory")

template <int KS>
__global__ __launch_bounds__(128) void snn_gemm_pw(
        const float* __restrict__ A, const float* __restrict__ W,
        float* __restrict__ P) {
    __shared__ float Aw[2][2][64 * BK];        // [wave][buf] 4 KB each
    __shared__ float Ww[2][2][BK * EXPERTS];   // [wave][buf] 4 KB each  -> 32 KB total

    const int t    = threadIdx.x;   // 0..127
    const int lane = t & 63;
    const int wv   = t >> 6;        // independent wave id
    const int rg   = lane >> 3;     // 0..7 : local rows rg*8..+7
    const int eg   = lane & 7;      // 0..7 : experts eg*8..+7
    const long row0 = (long)blockIdx.x * BM + (long)wv * 64;   // this wave's rows
    const int  k0   = blockIdx.y * KS;
    float* Pout = P + (long)blockIdx.y * ((long)T_TOTAL * EXPERTS);

    const float* aSrc[4];
#pragma unroll
    for (int p = 0; p < 4; ++p) {
        const int rl = p * 16 + (lane >> 2);
        const int cb = (lane & 3) ^ ((rl >> 3) & 3);
        aSrc[p] = &A[(row0 + rl) * HIDDEN + k0 + cb * 4];
    }
    const float* wSrc[4];
#pragma unroll
    for (int p = 0; p < 4; ++p)
        wSrc[p] = &W[(long)(k0 + p * 4 + (lane >> 4)) * EXPERTS + (lane & 15) * 4];

    auto stage = [&](int tile, int buf) {
        const int  aoff = tile * BK;
        const long woff = (long)tile * BK * EXPERTS;
#pragma unroll
        for (int p = 0; p < 4; ++p)
            GLOAD16(aSrc[p] + aoff, &Aw[wv][buf][p * 256]);   // +lane*16B by HW
#pragma unroll
        for (int p = 0; p < 4; ++p)
            GLOAD16(wSrc[p] + woff, &Ww[wv][buf][p * 256]);
    };

    float acc[8][8];
#pragma unroll
    for (int i = 0; i < 8; ++i)
#pragma unroll
        for (int j = 0; j < 8; ++j) acc[i][j] = 0.0f;

    stage(0, 0);

    constexpr int NTILE = KS / BK;
    int buf = 0;
    for (int tile = 0; tile < NTILE; ++tile) {
        if (tile + 1 < NTILE) {
            FENCE();
            stage(tile + 1, buf ^ 1);
            asm volatile("s_waitcnt vmcnt(8)" ::: "memory");   // tile t landed; t+1 in flight
        } else {
            asm volatile("s_waitcnt vmcnt(0)" ::: "memory");
        }
        FENCE();

        const float* ab = &Aw[wv][buf][0];
        const float* wb = &Ww[wv][buf][0];
        const int swz = rg & 3;
#pragma unroll
        for (int q = 0; q < BK / 4; ++q) {
            const int qs = (q ^ swz) * 4;
            float4 a4[8];
#pragma unroll
            for (int i = 0; i < 8; ++i)
                a4[i] = *reinterpret_cast<const float4*>(&ab[(rg * 8 + i) * BK + qs]);
            float4 w0[4], w1[4];
#pragma unroll
            for (int ki = 0; ki < 4; ++ki) {
                w0[ki] = *reinterpret_cast<const float4*>(&wb[(q * 4 + ki) * EXPERTS + eg * 8]);
                w1[ki] = *reinterpret_cast<const float4*>(&wb[(q * 4 + ki) * EXPERTS + eg * 8 + 4]);
            }
#pragma unroll
            for (int ki = 0; ki < 4; ++ki) {   // k ascending: q outer, ki inner
#pragma unroll
                for (int i = 0; i < 8; ++i) {
                    const float av = (&a4[i].x)[ki];
                    acc[i][0] = fmaf(av, w0[ki].x, acc[i][0]);
                    acc[i][1] = fmaf(av, w0[ki].y, acc[i][1]);
                    acc[i][2] = fmaf(av, w0[ki].z, acc[i][2]);
                    acc[i][3] = fmaf(av, w0[ki].w, acc[i][3]);
                    acc[i][4] = fmaf(av, w1[ki].x, acc[i][4]);
                    acc[i][5] = fmaf(av, w1[ki].y, acc[i][5]);
                    acc[i][6] = fmaf(av, w1[ki].z, acc[i][6]);
                    acc[i][7] = fmaf(av, w1[ki].w, acc[i][7]);
                }
            }
        }
        buf ^= 1;
    }

#pragma unroll
    for (int i = 0; i < 8; ++i) {
        float* base = &Pout[(row0 + rg * 8 + i) * EXPERTS + eg * 8];
        *reinterpret_cast<float4*>(base)     = make_float4(acc[i][0], acc[i][1], acc[i][2], acc[i][3]);
        *reinterpret_cast<float4*>(base + 4) = make_float4(acc[i][4], acc[i][5], acc[i][6], acc[i][7]);
    }
}

// ---- fixed-order split-K combine (template-unrolled: loads issued in parallel) ----
template <int NS>
__global__ __launch_bounds__(256) void snn_combine(const float* __restrict__ P,
                                                   float* __restrict__ cur) {
    const long i = (long)blockIdx.x * 256 + threadIdx.x;   // float4 index
    const float4* p = reinterpret_cast<const float4*>(P);
    float4 s = p[i];
#pragma unroll
    for (int k = 1; k < NS; ++k) {
        const float4 v = p[i + (long)k * (T_TOTAL * EXPERTS / 4)];
        s.x += v.x; s.y += v.y; s.z += v.z; s.w += v.w;
    }
    reinterpret_cast<float4*>(cur)[i] = s;
}

// ========= Scan: zero-sync overlap (warm-up 256 steps) + fused softmax =========
// NCHUNK 64 -> 128: 128 blocks over 256 CUs, serial chain 384 -> 320 steps. Warm-up
// stays >= 256 steps for w >= 4 (exact-from-zero for w < 4) -> trajectory bitwise
// unchanged vs R15. nwarm in {0,64,128,192,256}, all 32-aligned; nc even.
#define NCHUNK 128
#define CSTEPS (T_TOTAL / NCHUNK)   // 64
#define WARM   256

template <bool STORE>
__device__ __forceinline__ void lif_chunk(const float (&cbuf)[32], float* __restrict__ smp,
                                          int orow, int e, float& mp, float& refr) {
#pragma clang fp contract(off)
#pragma unroll
    for (int j = 0; j < 32; ++j) {
        const float term   = (refr <= 0.0f) ? cbuf[j] : 0.0f;
        const float mp_pre = mp * 0.9f + term;
        if constexpr (STORE) smp[(orow + j) * EXPERTS + e] = mp_pre;
        const bool spike = mp_pre > 1.0f;
        mp = spike ? 0.0f : mp_pre;
        const float rdec = fmaxf(refr - 0.1f, 0.0f);
        refr = spike ? 1.0f : rdec;
    }
}

__global__ __launch_bounds__(256) void snn_scan_ov(const float* __restrict__ cur,
                                                   float* __restrict__ out) {
    __shared__ float smp[CSTEPS * EXPERTS];   // 16 KB
    const int tid = threadIdx.x;
    const int w   = blockIdx.x;

    if (tid < 64) {
        const int e     = tid;
        const int t0abs = w * CSTEPS;
        const int s0    = (t0abs >= WARM) ? (t0abs - WARM) : 0;
        const int nwarm = t0abs - s0;              // 0..256, multiple of 64
        const int cwarm = nwarm >> 5;
        const int nc    = cwarm + (CSTEPS >> 5);   // even (2..10)
        const float* cb = cur + (long)s0 * EXPERTS + e;

        float mp = 0.0f, refr = 0.0f;
        float bufA[32], bufB[32];
#pragma unroll
        for (int j = 0; j < 32; ++j) bufA[j] = cb[j * EXPERTS] * 0.1f;

        for (int c2 = 0; c2 < nc; c2 += 2) {
            if (c2 + 1 < nc)
#pragma unroll
                for (int j = 0; j < 32; ++j) bufB[j] = cb[((c2 + 1) * 32 + j) * EXPERTS] * 0.1f;
            if (c2 >= cwarm) lif_chunk<true >(bufA, smp, c2 * 32 - nwarm, e, mp, refr);
            else             lif_chunk<false>(bufA, smp, 0, e, mp, refr);
            if (c2 + 2 < nc)
#pragma unroll
                for (int j = 0; j < 32; ++j) bufA[j] = cb[((c2 + 2) * 32 + j) * EXPERTS] * 0.1f;
            if (c2 + 1 >= cwarm) lif_chunk<true >(bufB, smp, (c2 + 1) * 32 - nwarm, e, mp, refr);
            else                 lif_chunk<false>(bufB, smp, 0, e, mp, refr);
        }
    }
    __syncthreads();

    // ---- fused routing softmax: wave wvid handles rows wvid*(CSTEPS/4) .. +CSTEPS/4 ----
    const int lane = tid & 63;
    const int wvid = tid >> 6;
    const float em1 = expf(-1.0f);
#pragma unroll 4
    for (int r = wvid * (CSTEPS / 4); r < (wvid + 1) * (CSTEPS / 4); ++r) {
        const float v = smp[r * EXPERTS + lane];
        const bool spike = v > 1.0f;
        const unsigned long long ball = __ballot(spike);
        float res;
        if (ball != 0ull) {
            const int n = __popcll(ball);
            const float denom = (float)n + (float)(EXPERTS - n) * em1;
            res = spike ? (1.0f / denom) : (em1 / denom);
        } else {
            float m = v;
#pragma unroll
            for (int off = 32; off >= 1; off >>= 1)
                m = fmaxf(m, __shfl_xor(m, off, 64));
            const float p = expf(v - m);
            float s = p;
#pragma unroll
            for (int off = 32; off >= 1; off >>= 1)
                s += __shfl_xor(s, off, 64);
            res = p / s;
        }
        out[((long)w * CSTEPS + r) * EXPERTS + lane] = res;
    }
}

// ---------------------------------------------------------------------------
extern "C" void kernel_launch(void* const* d_in, const int* in_sizes, int n_in,
                              void* d_out, int out_size, void* d_ws, size_t ws_size,
                              hipStream_t stream) {
    const float* hs = (const float*)d_in[0];   // [4,2048,2048] f32
    const float* w  = (const float*)d_in[1];   // [2048,64] f32
    float* out = (float*)d_out;                // [4,2048,64] f32

    char*  ws   = (char*)d_ws;
    float* cur  = (float*)(ws + (1u << 20));   // 2 MB @ 1 MB
    float* part = (float*)(ws + (4u << 20));   // up to 16 x 2 MB @ 4 MB

    const size_t slab = (size_t)T_TOTAL * EXPERTS * sizeof(float);   // 2 MB

    if (ws_size >= (4u << 20) + 16 * slab) {            // 36 MB (R10 evidence: ws ~262 MB)
        snn_gemm_pw<HIDDEN / 16><<<dim3(T_TOTAL / BM, 16), dim3(128), 0, stream>>>(hs, w, part);
        snn_combine<16><<<dim3(T_TOTAL * EXPERTS / 4 / 256), dim3(256), 0, stream>>>(part, cur);
    } else if (ws_size >= (4u << 20) + 8 * slab) {
        snn_gemm_pw<HIDDEN / 8><<<dim3(T_TOTAL / BM, 8), dim3(128), 0, stream>>>(hs, w, part);
        snn_combine<8><<<dim3(T_TOTAL * EXPERTS / 4 / 256), dim3(256), 0, stream>>>(part, cur);
    } else {
        snn_gemm_pw<HIDDEN><<<dim3(T_TOTAL / BM, 1), dim3(128), 0, stream>>>(hs, w, cur);
    }
    snn_scan_ov<<<dim3(NCHUNK), dim3(256), 0, stream>>>(cur, out);
}